// Round 7
// baseline (259.470 us; speedup 1.0000x reference)
//
#include <hip/hip_runtime.h>
#include <math.h>

#define BB 32
#define CC 256
#define HH 64
#define WW 64
#define HWSZ (HH * WW)   // 4096

typedef float f32x4 __attribute__((ext_vector_type(4)));

// ---------------------------------------------------------------------------
// Kernel 1: one pass over x.  (R6-measured-best form — unchanged.)
// Grid: 32 b x 4 position-quarters x 4 channel-quarters = 512 blocks.
// Wave w owns 16 channels over the quarter's 1024 positions; each channel
// read as a 4 KiB contiguous run. Pool partials per channel-quarter go to
// 4 separate buffer slabs -> no atomics; attn merges the 4 on read.
// ---------------------------------------------------------------------------
__global__ __launch_bounds__(256) void stats_kernel(
    const float* __restrict__ x, float* __restrict__ chan_part,
    float* __restrict__ pmax, float* __restrict__ psum) {
  const int b = blockIdx.x >> 4;
  const int q = (blockIdx.x >> 2) & 3;   // position quarter (1024 positions)
  const int cq = blockIdx.x & 3;         // channel quarter (64 channels)
  const int tid = threadIdx.x;
  const int wave = tid >> 6;
  const int lane = tid & 63;
  const int c0 = (cq << 6) + (wave << 4);  // first channel of this wave

  __shared__ float4 lmax[4][4][64];   // [wave][g][lane]
  __shared__ float4 lsum[4][4][64];

  float4 mx[4], sm[4];
#pragma unroll
  for (int g = 0; g < 4; ++g) {
    mx[g] = make_float4(-3.4e38f, -3.4e38f, -3.4e38f, -3.4e38f);
    sm[g] = make_float4(0.f, 0.f, 0.f, 0.f);
  }
  float own = 0.0f;   // lane ci ends up holding channel c0+ci's sum

  const float4* xb =
      (const float4*)(x + ((size_t)b << 20) + ((size_t)c0 << 12) + (q << 10)) + lane;

#pragma unroll 2
  for (int ci = 0; ci < 16; ++ci) {
    const float4* xc = xb + ci * (HWSZ / 4);
    const float4 v0 = xc[0];
    const float4 v1 = xc[64];
    const float4 v2 = xc[128];
    const float4 v3 = xc[192];

    mx[0].x = fmaxf(mx[0].x, v0.x); mx[0].y = fmaxf(mx[0].y, v0.y);
    mx[0].z = fmaxf(mx[0].z, v0.z); mx[0].w = fmaxf(mx[0].w, v0.w);
    mx[1].x = fmaxf(mx[1].x, v1.x); mx[1].y = fmaxf(mx[1].y, v1.y);
    mx[1].z = fmaxf(mx[1].z, v1.z); mx[1].w = fmaxf(mx[1].w, v1.w);
    mx[2].x = fmaxf(mx[2].x, v2.x); mx[2].y = fmaxf(mx[2].y, v2.y);
    mx[2].z = fmaxf(mx[2].z, v2.z); mx[2].w = fmaxf(mx[2].w, v2.w);
    mx[3].x = fmaxf(mx[3].x, v3.x); mx[3].y = fmaxf(mx[3].y, v3.y);
    mx[3].z = fmaxf(mx[3].z, v3.z); mx[3].w = fmaxf(mx[3].w, v3.w);

    sm[0].x += v0.x; sm[0].y += v0.y; sm[0].z += v0.z; sm[0].w += v0.w;
    sm[1].x += v1.x; sm[1].y += v1.y; sm[1].z += v1.z; sm[1].w += v1.w;
    sm[2].x += v2.x; sm[2].y += v2.y; sm[2].z += v2.z; sm[2].w += v2.w;
    sm[3].x += v3.x; sm[3].y += v3.y; sm[3].z += v3.z; sm[3].w += v3.w;

    float s = ((v0.x + v0.y) + (v0.z + v0.w)) + ((v1.x + v1.y) + (v1.z + v1.w)) +
              ((v2.x + v2.y) + (v2.z + v2.w)) + ((v3.x + v3.y) + (v3.z + v3.w));
#pragma unroll
    for (int off = 32; off > 0; off >>= 1) s += __shfl_xor(s, off, 64);
    if (lane == ci) own = s;
  }

  if (lane < 16)
    chan_part[(size_t)((b << 2) + q) * CC + c0 + lane] = own;

#pragma unroll
  for (int g = 0; g < 4; ++g) {
    lmax[wave][g][lane] = mx[g];
    lsum[wave][g][lane] = sm[g];
  }
  __syncthreads();

  {
    const int g = tid >> 6;
    const int l = tid & 63;
    const float4 a = lmax[0][g][l], b4 = lmax[1][g][l];
    const float4 c4 = lmax[2][g][l], d4 = lmax[3][g][l];
    float4 M;
    M.x = fmaxf(fmaxf(a.x, b4.x), fmaxf(c4.x, d4.x));
    M.y = fmaxf(fmaxf(a.y, b4.y), fmaxf(c4.y, d4.y));
    M.z = fmaxf(fmaxf(a.z, b4.z), fmaxf(c4.z, d4.z));
    M.w = fmaxf(fmaxf(a.w, b4.w), fmaxf(c4.w, d4.w));
    const float4 sa = lsum[0][g][l], sb = lsum[1][g][l];
    const float4 sc = lsum[2][g][l], sd = lsum[3][g][l];
    float4 S;
    S.x = (sa.x + sb.x) + (sc.x + sd.x);
    S.y = (sa.y + sb.y) + (sc.y + sd.y);
    S.z = (sa.z + sb.z) + (sc.z + sd.z);
    S.w = (sa.w + sb.w) + (sc.w + sd.w);
    const int f4 = ((cq * BB + b) << 10) + (q << 8) + (g << 6) + l;
    ((float4*)pmax)[f4] = M;
    ((float4*)psum)[f4] = S;
  }
}

// ---------------------------------------------------------------------------
// Kernel 2: blocks [0,32) = ECA (fold 4 q-partials, conv1d k=5, sigmoid);
// blocks [32,544) = spatial 7x7 conv + sigmoid over an LDS tile built by
// merging the four channel-quarter pool slabs (max / add).  (R6 form.)
// ---------------------------------------------------------------------------
__global__ __launch_bounds__(256) void attn_kernel(
    const float* __restrict__ chan_part, const float* __restrict__ w5,
    float* __restrict__ ch_w,
    const float* __restrict__ pmax, const float* __restrict__ psum,
    const float* __restrict__ w2, const float* __restrict__ bias,
    float* __restrict__ sp) {
  if (blockIdx.x < BB) {
    __shared__ float m[CC];
    const int b = blockIdx.x;
    const int c = threadIdx.x;
    float s = 0.0f;
#pragma unroll
    for (int k = 0; k < 4; ++k)
      s += chan_part[(size_t)((b << 2) + k) * CC + c];
    m[c] = s * (1.0f / HWSZ);
    __syncthreads();

    float acc = 0.0f;
#pragma unroll
    for (int k = 0; k < 5; ++k) {
      int cc = c + k - 2;
      float v = (cc >= 0 && cc < CC) ? m[cc] : 0.0f;
      acc = fmaf(v, w5[k], acc);
    }
    ch_w[b * CC + c] = 1.0f / (1.0f + __expf(-acc));
  } else {
    const int sblk = blockIdx.x - BB;     // 512 spatial blocks (4 rows each)
    const int b = sblk >> 4;
    const int chunk = sblk & 15;
    const int r0 = chunk << 2;
    const int tid = threadIdx.x;

    __shared__ float tmax[10][72];
    __shared__ float tsum[10][72];
    for (int idx = tid; idx < 720; idx += 256) {
      const int row = idx / 72;
      const int col = idx - row * 72;
      const int hh = r0 - 3 + row;
      const int wcol = col - 3;
      float vm = 0.0f, vs = 0.0f;
      if (hh >= 0 && hh < HH && wcol >= 0 && wcol < WW) {
        const int off = (b << 12) + (hh << 6) + wcol;
        const float m0 = pmax[off], m1 = pmax[(BB << 12) + off];
        const float m2 = pmax[(2 * BB << 12) + off], m3 = pmax[(3 * BB << 12) + off];
        vm = fmaxf(fmaxf(m0, m1), fmaxf(m2, m3));
        vs = (psum[off] + psum[(BB << 12) + off]) +
             (psum[(2 * BB << 12) + off] + psum[(3 * BB << 12) + off]);
      }
      tmax[row][col] = vm;
      tsum[row][col] = vs;
    }
    __syncthreads();

    const int lr = tid >> 6;
    const int w = tid & 63;
    float acc = bias[0];
#pragma unroll
    for (int kh = 0; kh < 7; ++kh) {
#pragma unroll
      for (int kw = 0; kw < 7; ++kw) {
        acc = fmaf(tmax[lr + kh][w + kw], w2[kh * 7 + kw], acc);
        acc = fmaf(tsum[lr + kh][w + kw], w2[49 + kh * 7 + kw] * (1.0f / CC), acc);
      }
    }
    sp[(b << 12) + (chunk << 8) + tid] = 1.0f / (1.0f + __expf(-acc));
  }
}

// ---------------------------------------------------------------------------
// Kernel 3: out = x * (ch_w[b,c] + sp[b,hw] + 1).
// RESTRUCTURED: 2048 blocks (32 b x 16 channel-groups x 4 hw-quarters);
// each thread processes 16 float4s, one per channel of its group, at a fixed
// hw position. 16 independent loads pipeline per thread (deep MLP), sp is
// read ONCE per thread and reused 16x from registers, ch_w is a wave-uniform
// scalar load per channel, and block count drops 16x (launch churn).
// ---------------------------------------------------------------------------
__global__ __launch_bounds__(256) void combine_kernel(
    const float* __restrict__ x, const float* __restrict__ ch_w,
    const float* __restrict__ sp, float* __restrict__ out) {
  const int blk = blockIdx.x;            // 2048 = 32b * 16cg * 4q
  const int b = blk >> 6;
  const int cg = (blk >> 2) & 15;        // 16 channels per block
  const int q = blk & 3;                 // 1024-position quarter
  const int t4 = threadIdx.x;            // float4 index within the quarter

  const float4 s4 = ((const float4*)(sp + ((size_t)b << 12) + (q << 10)))[t4];
  const size_t base = ((size_t)b << 20) + ((size_t)(cg << 4) << 12) + (q << 10);
  const float4* xb = (const float4*)(x + base) + t4;
  f32x4* ob = (f32x4*)(out + base) + t4;
  const float* cwp = ch_w + b * CC + (cg << 4);

#pragma unroll 4
  for (int ci = 0; ci < 16; ++ci) {
    const float cw = 1.0f + cwp[ci];     // block-uniform -> scalar load
    const float4 x4 = xb[ci << 10];      // channel stride = 1024 float4s
    f32x4 o;
    o.x = x4.x * (cw + s4.x);
    o.y = x4.y * (cw + s4.y);
    o.z = x4.z * (cw + s4.z);
    o.w = x4.w * (cw + s4.w);
    __builtin_nontemporal_store(o, ob + (ci << 10));
  }
}

extern "C" void kernel_launch(void* const* d_in, const int* in_sizes, int n_in,
                              void* d_out, int out_size, void* d_ws, size_t ws_size,
                              hipStream_t stream) {
  const float* x    = (const float*)d_in[0];  // (32,256,64,64)
  const float* w1   = (const float*)d_in[1];  // (1,1,5)
  const float* w2   = (const float*)d_in[2];  // (1,2,7,7)
  const float* bias = (const float*)d_in[3];  // (1,)
  float* out = (float*)d_out;

  float* ws = (float*)d_ws;
  float* chan_part = ws;                       // 32*4*256  = 32768 floats
  float* ch_w      = ws + 32768;               // 8192
  float* pmax      = ws + 40960;               // 4*131072 = 524288
  float* psum      = ws + 565248;              // 524288
  float* sp        = ws + 1089536;             // 131072
  // Every workspace word is written before it is read -> no memsets,
  // no atomics, no init-pattern dependence.

  stats_kernel<<<BB * 16, 256, 0, stream>>>(x, chan_part, pmax, psum);
  attn_kernel<<<BB + BB * 16, 256, 0, stream>>>(
      chan_part, w1, ch_w, pmax, psum, w2, bias, sp);
  combine_kernel<<<BB * 16 * 4, 256, 0, stream>>>(x, ch_w, sp, out);
}